// Round 16
// baseline (152.206 us; speedup 1.0000x reference)
//
#include <hip/hip_runtime.h>

#define FEPS 1e-12f

typedef __attribute__((ext_vector_type(8))) short short8;   // 8 bf16 = 4 VGPR
typedef __attribute__((ext_vector_type(4))) short bf16x4;   // 4 bf16 = 2 VGPR
typedef __attribute__((ext_vector_type(4))) float floatx4;  // MFMA C/D

constexpr int NB = 64, D = 256, T = 4096, K = 64, S = 8;
constexpr int TC = 64;           // pixels per chunk
constexpr int TBLK = T / S;      // 512 pixels per block
constexpr int NCH = TBLK / TC;   // 8 chunks

// f32 -> bf16 round-to-nearest-even
__device__ __forceinline__ unsigned short f2bf(float f) {
    unsigned u = __float_as_uint(f);
    return (unsigned short)((u + 0x7FFFu + ((u >> 16) & 1u)) >> 16);
}
__device__ __forceinline__ unsigned pk2(float a, float b) {
    return (unsigned)f2bf(a) | ((unsigned)f2bf(b) << 16);
}

// Workgroup barrier WITHOUT the implicit vmcnt(0) drain __syncthreads emits.
__device__ __forceinline__ void barrier_nd() {
    __builtin_amdgcn_sched_barrier(0);
    asm volatile("s_waitcnt lgkmcnt(0)" ::: "memory");
    __builtin_amdgcn_s_barrier();
    __builtin_amdgcn_sched_barrier(0);
}

// Fused: L2-norm factor + logits MFMA-GEMM + softmax + aggregation MFMA-GEMM
// + (last block per n) centroid-subtract + intra-norm + closed-form flat norm.
// R16: nv_finish_row is FUSED via a last-block-done handshake: after the
// atomic flush, __threadfence + per-n counter; the 8th block re-reads the
// accumulated vlad rows with AGENT-scope atomic loads (coherent vs the
// memory-side atomics; plain loads risk stale memset zeros in this XCD's L2),
// finishes, and writes final values. Saves the finish kernel launch + its
// 67MB HBM read (rows are L3-hot).
// nv_main structure = R13 (best stable): 3-barrier window, split pvA/pvB
// prefetch, tr-read GEMM1, JIT GEMM2 A-frags, t-major sqp.
// x tile LDS layout: byte(d,t)=(d>>5)*4096+(t>>4)*1024+(d&31)*32+(t&15)*2.
// TC=64: every global load = 4 rows x 256B contiguous. LDS ~75KB -> 2
// blocks/CU; __launch_bounds__(512,2) -> 128-VGPR cap (measured, no spill).
__global__ __launch_bounds__(512, 2)
void nv_main(const float* __restrict__ x, const float* __restrict__ w,
             const float* __restrict__ cent,
             float* __restrict__ vout, float* __restrict__ suma,
             int* __restrict__ cnt)
{
    __shared__ __align__(16) unsigned char smem[76800];
    // 0      .. 65536 : xt[2][32768]  x tiles (subtiled bf16, double-buffered)
    // 65536  .. 73728 : bm [k][64 t ^ 8(k&7)] bf16 (8 KB)
    // 73728  .. 74752 : sps[64 t][4] f32 softmax denom partials
    // 74752  .. 76800 : sqp[64 t][8 wv] f32 sumsq partials (t-major)
    unsigned short* bmm = (unsigned short*)(smem + 65536);
    float* sps = (float*)(smem + 73728);
    float* sqp = (float*)(smem + 74752);
    float* fb  = (float*)smem;
    __shared__ int lastflag;

    const int tid = threadIdx.x;
    const int wv = tid >> 6, ln = tid & 63;
    const int m = ln & 15, g = ln >> 4;     // MFMA/staging lane decomposition
    const int a = wv & 3, b = wv >> 2;      // GEMM1: k-band a, t-half b
    const int bid = blockIdx.x;
    const int n = (bid & 7) * 8 + ((bid >> 3) & 7);   // XCD-confined n octet
    const int ts = bid >> 6;                           // t-split 0..7

    const float* xn = x + (size_t)n * D * T;

    // Resident W A-frags for k-band a = [16a, 16a+16)
    short8 wf[8];
    {
        const float* wp = w + (16 * a + m) * D + 8 * g;
        #pragma unroll
        for (int ks = 0; ks < 8; ++ks) {
            float4 q0 = *(const float4*)(wp + 32 * ks);
            float4 q1 = *(const float4*)(wp + 32 * ks + 4);
            union { short8 v; unsigned u[4]; } t_;
            t_.u[0] = pk2(q0.x, q0.y); t_.u[1] = pk2(q0.z, q0.w);
            t_.u[2] = pk2(q1.x, q1.y); t_.u[3] = pk2(q1.z, q1.w);
            wf[ks] = t_.v;
        }
    }

    floatx4 acc[4][2];                       // GEMM2 acc [mt(k)][nt2(d)]
    floatx4 fzero = {0.f, 0.f, 0.f, 0.f};
    #pragma unroll
    for (int p = 0; p < 4; ++p) { acc[p][0] = fzero; acc[p][1] = fzero; }
    float sa[4] = {0.f, 0.f, 0.f, 0.f};      // sum_t a for k = 16a+4g+reg

    float4 pvA[4], pvB[4];                   // split prefetch buffers
    float4 sq4;                              // sumsq carry stageA->stageB

    // issue half H (rows s0..s0+3) of chunk cc
    auto issueH = [&](float4* pv, int cc, int s0) {
        const int tn = ts * TBLK + cc * TC;
        #pragma unroll
        for (int s = 0; s < 4; ++s)
            pv[s] = *(const float4*)(
                xn + (size_t)(32 * wv + 4 * (s0 + s) + g) * T + tn + 4 * m);
    };
    // stage half H into xt[bufsel] (subtiled bf16), accumulate sq4
    auto stageH = [&](const float4* pv, int bufsel, int s0) {
        #pragma unroll
        for (int s = 0; s < 4; ++s) {
            float4 v = pv[s];
            sq4.x = fmaf(v.x, v.x, sq4.x); sq4.y = fmaf(v.y, v.y, sq4.y);
            sq4.z = fmaf(v.z, v.z, sq4.z); sq4.w = fmaf(v.w, v.w, sq4.w);
            uint2 st2; st2.x = pk2(v.x, v.y); st2.y = pk2(v.z, v.w);
            const int dd = 4 * (s0 + s) + g;     // d & 31 (d = 32wv + dd)
            *(uint2*)(smem + bufsel * 32768 + wv * 4096 + (m >> 2) * 1024
                      + dd * 32 + (m & 3) * 8) = st2;
        }
    };
    auto sqzero = [&]() {
        sq4.x = 0.f; sq4.y = 0.f; sq4.z = 0.f; sq4.w = 0.f;
    };
    auto sqreduce = [&]() {                  // reduce over g, publish t-major
        #pragma unroll
        for (int msk = 16; msk <= 32; msk <<= 1) {
            sq4.x += __shfl_xor(sq4.x, msk); sq4.y += __shfl_xor(sq4.y, msk);
            sq4.z += __shfl_xor(sq4.z, msk); sq4.w += __shfl_xor(sq4.w, msk);
        }
        if (g == 0) {
            sqp[(4 * m + 0) * 8 + wv] = sq4.x;
            sqp[(4 * m + 1) * 8 + wv] = sq4.y;
            sqp[(4 * m + 2) * 8 + wv] = sq4.z;
            sqp[(4 * m + 3) * 8 + wv] = sq4.w;
        }
    };

    // ---- prologue: load + stage chunk 0 into xt[0]
    issueH(pvA, 0, 0); issueH(pvB, 0, 4);
    sqzero();
    stageH(pvA, 0, 0); stageH(pvB, 0, 4);
    sqreduce();

    for (int c = 0; c < NCH; ++c) {
        const int cur = c & 1;
        barrier_nd();                        // B_A: publish xt[cur] + sqp

        // ---- issueA for chunk c+1 (in flight across whole window)
        if (c + 1 < NCH) issueH(pvA, c + 1, 0);

        // ---- r[t] = 1/max(||x[:,t]||,eps): 2 x b128 per t (t-major sqp)
        float r4[2];
        #pragma unroll
        for (int nt = 0; nt < 2; ++nt) {
            const int t = 32 * b + 16 * nt + m;
            float4 p0 = *(const float4*)(&sqp[t * 8]);
            float4 p1 = *(const float4*)(&sqp[t * 8 + 4]);
            float ss = ((p0.x + p0.y) + (p0.z + p0.w))
                     + ((p1.x + p1.y) + (p1.z + p1.w));
            r4[nt] = 1.f / fmaxf(sqrtf(ss), FEPS);
        }
        asm volatile("s_waitcnt lgkmcnt(0)" ::: "memory");
        __builtin_amdgcn_sched_barrier(0);

        // ---- GEMM1: z[16 k][32 t] = W * x, B-frags via HW transpose-read.
        floatx4 z[2];
        z[0] = fzero; z[1] = fzero;
        const int trb = cur * 32768 + 2048 * b + 256 * g + 2 * m;
        bf16x4 hb[2][2][2];                  // [pipe][nt][half]
        {
            asm volatile("ds_read_b64_tr_b16 %0, %2 offset:0\n\t"
                         "ds_read_b64_tr_b16 %1, %2 offset:128"
                         : "=&v"(hb[0][0][0]), "=&v"(hb[0][0][1])
                         : "v"(trb));
            asm volatile("ds_read_b64_tr_b16 %0, %2 offset:0\n\t"
                         "ds_read_b64_tr_b16 %1, %2 offset:128"
                         : "=&v"(hb[0][1][0]), "=&v"(hb[0][1][1])
                         : "v"(trb + 1024));
        }
        #pragma unroll
        for (int ks = 0; ks < 8; ++ks) {
            const int pc = ks & 1;
            if (ks < 7) {
                const int an = trb + (ks + 1) * 4096;
                asm volatile("ds_read_b64_tr_b16 %0, %2 offset:0\n\t"
                             "ds_read_b64_tr_b16 %1, %2 offset:128"
                             : "=&v"(hb[pc ^ 1][0][0]), "=&v"(hb[pc ^ 1][0][1])
                             : "v"(an));
                asm volatile("ds_read_b64_tr_b16 %0, %2 offset:0\n\t"
                             "ds_read_b64_tr_b16 %1, %2 offset:128"
                             : "=&v"(hb[pc ^ 1][1][0]), "=&v"(hb[pc ^ 1][1][1])
                             : "v"(an + 1024));
                asm volatile("s_waitcnt lgkmcnt(4)" ::: "memory");
            } else {
                asm volatile("s_waitcnt lgkmcnt(0)" ::: "memory");
            }
            __builtin_amdgcn_sched_barrier(0);
            #pragma unroll
            for (int nt = 0; nt < 2; ++nt) {
                short8 bfr = __builtin_shufflevector(
                    hb[pc][nt][0], hb[pc][nt][1], 0, 1, 2, 3, 4, 5, 6, 7);
                z[nt] = __builtin_amdgcn_mfma_f32_16x16x32_bf16(
                    wf[ks], bfr, z[nt], 0, 0, 0);
            }
        }

        // ---- issueB for chunk c+1 (second burst; flight ~half window)
        if (c + 1 < NCH) issueH(pvB, c + 1, 4);

        // ---- softmax over k (no max-sub: |logit| <= ||w_row|| ~ 1)
        float e[2][4], psum[2];
        #pragma unroll
        for (int nt = 0; nt < 2; ++nt) {
            const float r = r4[nt];
            float p = 0.f;
            #pragma unroll
            for (int reg = 0; reg < 4; ++reg) {
                float ex = __expf(z[nt][reg] * r);
                e[nt][reg] = ex; p += ex;
            }
            psum[nt] = p;
        }
        #pragma unroll
        for (int nt = 0; nt < 2; ++nt) {     // reduce over g: wave's 16 k's
            psum[nt] += __shfl_xor(psum[nt], 16);
            psum[nt] += __shfl_xor(psum[nt], 32);
        }
        if (g == 0) {
            #pragma unroll
            for (int nt = 0; nt < 2; ++nt)
                sps[(32 * b + 16 * nt + m) * 4 + a] = psum[nt];
        }
        barrier_nd();                        // B_B: publish sps
        #pragma unroll
        for (int nt = 0; nt < 2; ++nt) {
            const int t = 32 * b + 16 * nt + m;
            float4 sv = *(const float4*)(&sps[t * 4]);
            const float inv = 1.f / (sv.x + sv.y + sv.z + sv.w);
            const float br = inv * r4[nt];
            #pragma unroll
            for (int reg = 0; reg < 4; ++reg) {
                const int k = 16 * a + 4 * g + reg;
                bmm[k * TC + (t ^ (8 * (k & 7)))] = f2bf(e[nt][reg] * br);
                sa[reg] += e[nt][reg] * inv;
            }
        }

        // ---- stageA chunk c+1 -> xt[cur^1] (free since B_A)
        sqzero();
        if (c + 1 < NCH) stageH(pvA, cur ^ 1, 0);
        barrier_nd();                        // B_C: publish bm

        // ---- GEMM2: acc[k][d] += b[k][t] * x[d][t]  (contract t=64)
        #pragma unroll
        for (int kt = 0; kt < 2; ++kt) {
            short8 bf[2];
            #pragma unroll
            for (int nt2 = 0; nt2 < 2; ++nt2)
                bf[nt2] = *(const short8*)(smem + cur * 32768 + wv * 4096
                           + (2 * kt + (g >> 1)) * 1024
                           + (16 * nt2 + m) * 32 + (g & 1) * 16);
            #pragma unroll
            for (int mt = 0; mt < 4; ++mt) {
                const int k = 16 * mt + m;
                short8 af = *(const short8*)(
                    &bmm[k * TC + ((32 * kt + 8 * g) ^ (8 * (k & 7)))]);
                #pragma unroll
                for (int nt2 = 0; nt2 < 2; ++nt2)
                    acc[mt][nt2] = __builtin_amdgcn_mfma_f32_16x16x32_bf16(
                        af, bf[nt2], acc[mt][nt2], 0, 0, 0);
            }
        }

        // ---- stageB chunk c+1; publish sqp for next window
        if (c + 1 < NCH) { stageH(pvB, cur ^ 1, 4); sqreduce(); }
    }

    // ---- flush: reassemble block partial in LDS, 256B-burst atomics
    barrier_nd();                            // xt dead -> reuse as fb [k][d]
    #pragma unroll
    for (int mt = 0; mt < 4; ++mt)
        #pragma unroll
        for (int nt2 = 0; nt2 < 2; ++nt2)
            #pragma unroll
            for (int reg = 0; reg < 4; ++reg)
                fb[(16 * mt + 4 * g + reg) * D + 32 * wv + 16 * nt2 + m] =
                    acc[mt][nt2][reg];
    barrier_nd();
    float* vs = vout + (size_t)n * K * D;
    #pragma unroll
    for (int j = 0; j < 32; ++j) {
        const int off = wv * 2048 + j * 64 + ln;  // 64 lanes x 4B = 256B
        atomicAdd(&vs[off], fb[off]);
    }
    #pragma unroll
    for (int reg = 0; reg < 4; ++reg) {
        float v = sa[reg];
        v += __shfl_xor(v, 1); v += __shfl_xor(v, 2);
        v += __shfl_xor(v, 4); v += __shfl_xor(v, 8);
        if (m == 0) atomicAdd(&suma[n * K + 16 * a + 4 * g + reg], v);
    }

    // ---- last-block-done handshake: 8th block for this n finishes it
    __threadfence();                         // release our atomics
    if (tid == 0) lastflag = (atomicAdd(&cnt[n], 1) == S - 1) ? 1 : 0;
    __syncthreads();
    if (lastflag) {
        __threadfence();                     // acquire others' atomics
        #pragma unroll
        for (int r = 0; r < 8; ++r) {
            const int row = wv * 8 + r;      // k = row
            const float sm = __hip_atomic_load(&suma[n * K + row],
                                __ATOMIC_RELAXED, __HIP_MEMORY_SCOPE_AGENT);
            float v0[4];
            float sv = 0.f;
            #pragma unroll
            for (int j = 0; j < 4; ++j) {
                const int idx = row * D + 64 * j + ln;
                float val = __hip_atomic_load(&vs[idx],
                                __ATOMIC_RELAXED, __HIP_MEMORY_SCOPE_AGENT);
                v0[j] = val - sm * cent[row * D + 64 * j + ln];
                sv = fmaf(v0[j], v0[j], sv);
            }
            #pragma unroll
            for (int msk = 1; msk < 64; msk <<= 1)
                sv += __shfl_xor(sv, msk);
            // intra-norm * closed-form flat norm 1/sqrt(K): rows are unit
            // after intra-norm, so ||flat|| = sqrt(K) = 8 exactly.
            const float inv = 0.125f / fmaxf(sqrtf(sv), FEPS);
            #pragma unroll
            for (int j = 0; j < 4; ++j)
                vs[row * D + 64 * j + ln] = v0[j] * inv;
        }
    }
}

extern "C" void kernel_launch(void* const* d_in, const int* in_sizes, int n_in,
                              void* d_out, int out_size, void* d_ws, size_t ws_size,
                              hipStream_t stream)
{
    const float* x    = (const float*)d_in[0];
    const float* w    = (const float*)d_in[1];
    const float* cent = (const float*)d_in[2];
    float* out = (float*)d_out;

    // ws layout: suma[NB*K] f32 | cnt[NB] int
    float* suma = (float*)d_ws;
    int*   cnt  = (int*)((char*)d_ws + (size_t)NB * K * sizeof(float));

    (void)hipMemsetAsync(d_ws, 0, (size_t)(NB * K + NB) * 4, stream);
    (void)hipMemsetAsync(d_out, 0, (size_t)NB * K * D * sizeof(float), stream);

    nv_main<<<S * NB, 512, 0, stream>>>(x, w, cent, out, suma, cnt);
}

// Round 17
// 95.241 us; speedup vs baseline: 1.5981x; 1.5981x over previous
//
#include <hip/hip_runtime.h>

#define FEPS 1e-12f

typedef __attribute__((ext_vector_type(8))) short short8;   // 8 bf16 = 4 VGPR
typedef __attribute__((ext_vector_type(4))) short bf16x4;   // 4 bf16 = 2 VGPR
typedef __attribute__((ext_vector_type(4))) float floatx4;  // MFMA C/D

constexpr int NB = 64, D = 256, T = 4096, K = 64, S = 8;
constexpr int TC = 64;           // pixels per chunk
constexpr int TBLK = T / S;      // 512 pixels per block
constexpr int NCH = TBLK / TC;   // 8 chunks

// f32 -> bf16 round-to-nearest-even
__device__ __forceinline__ unsigned short f2bf(float f) {
    unsigned u = __float_as_uint(f);
    return (unsigned short)((u + 0x7FFFu + ((u >> 16) & 1u)) >> 16);
}
__device__ __forceinline__ unsigned pk2(float a, float b) {
    return (unsigned)f2bf(a) | ((unsigned)f2bf(b) << 16);
}

// Workgroup barrier WITHOUT the implicit vmcnt(0) drain __syncthreads emits.
__device__ __forceinline__ void barrier_nd() {
    __builtin_amdgcn_sched_barrier(0);
    asm volatile("s_waitcnt lgkmcnt(0)" ::: "memory");
    __builtin_amdgcn_s_barrier();
    __builtin_amdgcn_sched_barrier(0);
}

// Fused: L2-norm factor + logits MFMA-GEMM + softmax + aggregation MFMA-GEMM.
// R17 = R15 (97.2us best) + max-flight prefetch: each pv buffer is REISSUED
// immediately after its stage consumes it (issueA(c+2) right after
// stageA(c+1), issueB(c+2) right after stageB(c+1)) -> every load burst is
// in flight for a full window instead of ~half. Little's-law: avg in-flight
// bytes/CU ~doubles (70->128KB) -> delivered BW rises toward fair share.
// Same registers (each buffer holds exactly one chunk at a time).
// x tile in LDS in tr-read subtile layout:
//   byte(d,t) = (d>>5)*4096 + (t>>4)*1024 + (d&31)*32 + (t&15)*2  [32x16 bf16]
// TC=64: every global load = 4 rows x 256B contiguous. LDS 75KB -> 2
// blocks/CU; __launch_bounds__(512,2) -> 128-VGPR cap (measured, no spill).
__global__ __launch_bounds__(512, 2)
void nv_main(const float* __restrict__ x, const float* __restrict__ w,
             float* __restrict__ vout, float* __restrict__ suma)
{
    __shared__ __align__(16) unsigned char smem[76800];
    // 0      .. 65536 : xt[2][32768]  x tiles (subtiled bf16, double-buffered)
    // 65536  .. 73728 : bm [k][64 t ^ 8(k&7)] bf16 (8 KB)
    // 73728  .. 74752 : sps[64 t][4] f32 softmax denom partials
    // 74752  .. 76800 : sqp[64 t][8 wv] f32 sumsq partials (t-major)
    unsigned short* bmm = (unsigned short*)(smem + 65536);
    float* sps = (float*)(smem + 73728);
    float* sqp = (float*)(smem + 74752);
    float* fb  = (float*)smem;

    const int tid = threadIdx.x;
    const int wv = tid >> 6, ln = tid & 63;
    const int m = ln & 15, g = ln >> 4;     // MFMA/staging lane decomposition
    const int a = wv & 3, b = wv >> 2;      // GEMM1: k-band a, t-half b
    const int bid = blockIdx.x;
    const int n = (bid & 7) * 8 + ((bid >> 3) & 7);   // XCD-confined n octet
    const int ts = bid >> 6;                           // t-split 0..7

    const float* xn = x + (size_t)n * D * T;

    // Resident W A-frags for k-band a = [16a, 16a+16)
    short8 wf[8];
    {
        const float* wp = w + (16 * a + m) * D + 8 * g;
        #pragma unroll
        for (int ks = 0; ks < 8; ++ks) {
            float4 q0 = *(const float4*)(wp + 32 * ks);
            float4 q1 = *(const float4*)(wp + 32 * ks + 4);
            union { short8 v; unsigned u[4]; } t_;
            t_.u[0] = pk2(q0.x, q0.y); t_.u[1] = pk2(q0.z, q0.w);
            t_.u[2] = pk2(q1.x, q1.y); t_.u[3] = pk2(q1.z, q1.w);
            wf[ks] = t_.v;
        }
    }

    floatx4 acc[4][2];                       // GEMM2 acc [mt(k)][nt2(d)]
    floatx4 fzero = {0.f, 0.f, 0.f, 0.f};
    #pragma unroll
    for (int p = 0; p < 4; ++p) { acc[p][0] = fzero; acc[p][1] = fzero; }
    float sa[4] = {0.f, 0.f, 0.f, 0.f};      // sum_t a for k = 16a+4g+reg

    float4 pvA[4], pvB[4];                   // split prefetch buffers
    float4 sq4;                              // sumsq carry stageA->stageB

    // issue half H (rows s0..s0+3) of chunk cc
    auto issueH = [&](float4* pv, int cc, int s0) {
        const int tn = ts * TBLK + cc * TC;
        #pragma unroll
        for (int s = 0; s < 4; ++s)
            pv[s] = *(const float4*)(
                xn + (size_t)(32 * wv + 4 * (s0 + s) + g) * T + tn + 4 * m);
    };
    // stage half H into xt[bufsel] (subtiled bf16), accumulate sq4
    auto stageH = [&](const float4* pv, int bufsel, int s0) {
        #pragma unroll
        for (int s = 0; s < 4; ++s) {
            float4 v = pv[s];
            sq4.x = fmaf(v.x, v.x, sq4.x); sq4.y = fmaf(v.y, v.y, sq4.y);
            sq4.z = fmaf(v.z, v.z, sq4.z); sq4.w = fmaf(v.w, v.w, sq4.w);
            uint2 st2; st2.x = pk2(v.x, v.y); st2.y = pk2(v.z, v.w);
            const int dd = 4 * (s0 + s) + g;     // d & 31 (d = 32wv + dd)
            *(uint2*)(smem + bufsel * 32768 + wv * 4096 + (m >> 2) * 1024
                      + dd * 32 + (m & 3) * 8) = st2;
        }
    };
    auto sqzero = [&]() {
        sq4.x = 0.f; sq4.y = 0.f; sq4.z = 0.f; sq4.w = 0.f;
    };
    auto sqreduce = [&]() {                  // reduce over g, publish t-major
        #pragma unroll
        for (int msk = 16; msk <= 32; msk <<= 1) {
            sq4.x += __shfl_xor(sq4.x, msk); sq4.y += __shfl_xor(sq4.y, msk);
            sq4.z += __shfl_xor(sq4.z, msk); sq4.w += __shfl_xor(sq4.w, msk);
        }
        if (g == 0) {
            sqp[(4 * m + 0) * 8 + wv] = sq4.x;
            sqp[(4 * m + 1) * 8 + wv] = sq4.y;
            sqp[(4 * m + 2) * 8 + wv] = sq4.z;
            sqp[(4 * m + 3) * 8 + wv] = sq4.w;
        }
    };

    // ---- prologue: load + stage chunk 0 into xt[0]; put chunk 1 in flight
    issueH(pvA, 0, 0); issueH(pvB, 0, 4);
    sqzero();
    stageH(pvA, 0, 0); stageH(pvB, 0, 4);
    sqreduce();
    issueH(pvA, 1, 0); issueH(pvB, 1, 4);    // NCH >= 2

    for (int c = 0; c < NCH; ++c) {
        const int cur = c & 1;
        barrier_nd();                        // B_A: publish xt[cur] + sqp

        // ---- r[t] = 1/max(||x[:,t]||,eps): 2 x b128 per t (t-major sqp)
        float r4[2];
        #pragma unroll
        for (int nt = 0; nt < 2; ++nt) {
            const int t = 32 * b + 16 * nt + m;
            float4 p0 = *(const float4*)(&sqp[t * 8]);
            float4 p1 = *(const float4*)(&sqp[t * 8 + 4]);
            float ss = ((p0.x + p0.y) + (p0.z + p0.w))
                     + ((p1.x + p1.y) + (p1.z + p1.w));
            r4[nt] = 1.f / fmaxf(sqrtf(ss), FEPS);
        }
        asm volatile("s_waitcnt lgkmcnt(0)" ::: "memory");
        __builtin_amdgcn_sched_barrier(0);

        // ---- GEMM1: z[16 k][32 t] = W * x, B-frags via HW transpose-read.
        floatx4 z[2];
        z[0] = fzero; z[1] = fzero;
        const int trb = cur * 32768 + 2048 * b + 256 * g + 2 * m;
        bf16x4 hb[2][2][2];                  // [pipe][nt][half]
        {
            asm volatile("ds_read_b64_tr_b16 %0, %2 offset:0\n\t"
                         "ds_read_b64_tr_b16 %1, %2 offset:128"
                         : "=&v"(hb[0][0][0]), "=&v"(hb[0][0][1])
                         : "v"(trb));
            asm volatile("ds_read_b64_tr_b16 %0, %2 offset:0\n\t"
                         "ds_read_b64_tr_b16 %1, %2 offset:128"
                         : "=&v"(hb[0][1][0]), "=&v"(hb[0][1][1])
                         : "v"(trb + 1024));
        }
        #pragma unroll
        for (int ks = 0; ks < 8; ++ks) {
            const int pc = ks & 1;
            if (ks < 7) {
                const int an = trb + (ks + 1) * 4096;
                asm volatile("ds_read_b64_tr_b16 %0, %2 offset:0\n\t"
                             "ds_read_b64_tr_b16 %1, %2 offset:128"
                             : "=&v"(hb[pc ^ 1][0][0]), "=&v"(hb[pc ^ 1][0][1])
                             : "v"(an));
                asm volatile("ds_read_b64_tr_b16 %0, %2 offset:0\n\t"
                             "ds_read_b64_tr_b16 %1, %2 offset:128"
                             : "=&v"(hb[pc ^ 1][1][0]), "=&v"(hb[pc ^ 1][1][1])
                             : "v"(an + 1024));
                asm volatile("s_waitcnt lgkmcnt(4)" ::: "memory");
            } else {
                asm volatile("s_waitcnt lgkmcnt(0)" ::: "memory");
            }
            __builtin_amdgcn_sched_barrier(0);
            #pragma unroll
            for (int nt = 0; nt < 2; ++nt) {
                short8 bfr = __builtin_shufflevector(
                    hb[pc][nt][0], hb[pc][nt][1], 0, 1, 2, 3, 4, 5, 6, 7);
                z[nt] = __builtin_amdgcn_mfma_f32_16x16x32_bf16(
                    wf[ks], bfr, z[nt], 0, 0, 0);
            }
        }

        // ---- softmax over k (no max-sub: |logit| <= ||w_row|| ~ 1)
        float e[2][4], psum[2];
        #pragma unroll
        for (int nt = 0; nt < 2; ++nt) {
            const float r = r4[nt];
            float p = 0.f;
            #pragma unroll
            for (int reg = 0; reg < 4; ++reg) {
                float ex = __expf(z[nt][reg] * r);
                e[nt][reg] = ex; p += ex;
            }
            psum[nt] = p;
        }
        #pragma unroll
        for (int nt = 0; nt < 2; ++nt) {     // reduce over g: wave's 16 k's
            psum[nt] += __shfl_xor(psum[nt], 16);
            psum[nt] += __shfl_xor(psum[nt], 32);
        }
        if (g == 0) {
            #pragma unroll
            for (int nt = 0; nt < 2; ++nt)
                sps[(32 * b + 16 * nt + m) * 4 + a] = psum[nt];
        }
        barrier_nd();                        // B_B: publish sps
        #pragma unroll
        for (int nt = 0; nt < 2; ++nt) {
            const int t = 32 * b + 16 * nt + m;
            float4 sv = *(const float4*)(&sps[t * 4]);
            const float inv = 1.f / (sv.x + sv.y + sv.z + sv.w);
            const float br = inv * r4[nt];
            #pragma unroll
            for (int reg = 0; reg < 4; ++reg) {
                const int k = 16 * a + 4 * g + reg;
                bmm[k * TC + (t ^ (8 * (k & 7)))] = f2bf(e[nt][reg] * br);
                sa[reg] += e[nt][reg] * inv;
            }
        }

        // ---- stageA chunk c+1 -> xt[cur^1]; REISSUE pvA with chunk c+2
        sqzero();
        if (c + 1 < NCH) stageH(pvA, cur ^ 1, 0);
        if (c + 2 < NCH) issueH(pvA, c + 2, 0);
        barrier_nd();                        // B_C: publish bm

        // ---- GEMM2: acc[k][d] += b[k][t] * x[d][t]  (contract t=64)
        #pragma unroll
        for (int kt = 0; kt < 2; ++kt) {
            short8 bf[2];
            #pragma unroll
            for (int nt2 = 0; nt2 < 2; ++nt2)
                bf[nt2] = *(const short8*)(smem + cur * 32768 + wv * 4096
                           + (2 * kt + (g >> 1)) * 1024
                           + (16 * nt2 + m) * 32 + (g & 1) * 16);
            #pragma unroll
            for (int mt = 0; mt < 4; ++mt) {
                const int k = 16 * mt + m;
                short8 af = *(const short8*)(
                    &bmm[k * TC + ((32 * kt + 8 * g) ^ (8 * (k & 7)))]);
                #pragma unroll
                for (int nt2 = 0; nt2 < 2; ++nt2)
                    acc[mt][nt2] = __builtin_amdgcn_mfma_f32_16x16x32_bf16(
                        af, bf[nt2], acc[mt][nt2], 0, 0, 0);
            }
        }

        // ---- stageB chunk c+1; publish sqp; REISSUE pvB with chunk c+2
        if (c + 1 < NCH) { stageH(pvB, cur ^ 1, 4); sqreduce(); }
        if (c + 2 < NCH) issueH(pvB, c + 2, 4);
    }

    // ---- epilogue: reassemble block partial in LDS, flush with 256B bursts
    barrier_nd();                            // xt dead -> reuse as fb [k][d]
    #pragma unroll
    for (int mt = 0; mt < 4; ++mt)
        #pragma unroll
        for (int nt2 = 0; nt2 < 2; ++nt2)
            #pragma unroll
            for (int reg = 0; reg < 4; ++reg)
                fb[(16 * mt + 4 * g + reg) * D + 32 * wv + 16 * nt2 + m] =
                    acc[mt][nt2][reg];
    barrier_nd();
    {
        float* vs = vout + (size_t)n * K * D;
        #pragma unroll
        for (int j = 0; j < 32; ++j) {
            const int off = wv * 2048 + j * 64 + ln;  // 64 lanes x 4B = 256B
            atomicAdd(&vs[off], fb[off]);
        }
    }
    #pragma unroll
    for (int reg = 0; reg < 4; ++reg) {
        float v = sa[reg];
        v += __shfl_xor(v, 1); v += __shfl_xor(v, 2);
        v += __shfl_xor(v, 4); v += __shfl_xor(v, 8);
        if (m == 0) atomicAdd(&suma[n * K + 16 * a + 4 * g + reg], v);
    }
}

// per (n,k): subtract suma*centroid, intra-normalize over d, and apply the
// final flat L2 in closed form: after intra-norm every row has unit norm, so
// ||flat|| = sqrt(K) = 8 exactly -> fold 1/8 here and skip the extra pass.
__global__ void nv_finish_row(const float* __restrict__ cent,
                              const float* __restrict__ suma,
                              float* __restrict__ out)
{
    const int bid = blockIdx.x;          // n*64 + k
    const int k = bid & 63;
    const int d = threadIdx.x;
    float v = out[(size_t)bid * D + d] - suma[bid] * cent[k * D + d];
    float sv = v * v;
    #pragma unroll
    for (int msk = 1; msk < 64; msk <<= 1) sv += __shfl_xor(sv, msk);
    __shared__ float red[4];
    __shared__ float stot;
    if ((d & 63) == 0) red[d >> 6] = sv;
    __syncthreads();
    if (d == 0) stot = red[0] + red[1] + red[2] + red[3];
    __syncthreads();
    const float inv = 0.125f / fmaxf(sqrtf(stot), FEPS);   // intra-norm * 1/sqrt(K)
    out[(size_t)bid * D + d] = v * inv;
}

extern "C" void kernel_launch(void* const* d_in, const int* in_sizes, int n_in,
                              void* d_out, int out_size, void* d_ws, size_t ws_size,
                              hipStream_t stream)
{
    const float* x    = (const float*)d_in[0];
    const float* w    = (const float*)d_in[1];
    const float* cent = (const float*)d_in[2];
    float* out = (float*)d_out;

    float* suma = (float*)d_ws;          // NB*K floats

    (void)hipMemsetAsync(d_ws, 0, (size_t)NB * K * sizeof(float), stream);
    (void)hipMemsetAsync(d_out, 0, (size_t)NB * K * D * sizeof(float), stream);

    nv_main<<<S * NB, 512, 0, stream>>>(x, w, out, suma);
    nv_finish_row<<<NB * K, 256, 0, stream>>>(cent, suma, out);
}